// Round 15
// baseline (78.135 us; speedup 1.0000x reference)
//
#include <hip/hip_runtime.h>
#include <hip/hip_bf16.h>

// out[m, n] = sum_{e : rows[e]==m} vals[e] * A[cols[e], n]
// M = 100000, K = 100000, N = 64, NNZ = 1600000
//
// Round 15: soft shard alignment — row-major/shard-minor sort key.
//  Evidence: R11/R13 shard-phased both hit FETCH 117-119 MB = compulsory
//  floor (8 XCDs x 12.8 MB A + pvc), but R11's per-shard loops added
//  divergence (~9us). Key (rl<<3)|shard keeps each group's run CONTIGUOUS
//  (R14's divergence-free batched loop unchanged) while ordering entries
//  column-ascending within the run -> lockstep groups sweep A in soft
//  phase alignment (live set ~2-3 MB/XCD ~ L2).

#define NCOLS      64
#define RPB        64
#define RPB_SHIFT  6
#define NBLK       256         // sort blocks == reduce BT (1 sub-seg per thread)
#define BT         256
#define BT_S       1024        // sort block threads
#define CAP_S      8192        // sort chunk entries (64 KB LDS)
#define CAP_R      2048        // reduce staging entries (16 KB LDS)
#define SCAP       12          // register-staged entries per sub-segment
#define MAXNB      1568
#define SH_SHIFT   14          // shard = col >> 14 (2 MB bf16 A-region)
#define NKEY       512         // RPB * 8 shards

// ---- fallback (round-1 kernel) ----
__global__ void spmm_scatter_atomic(const float* __restrict__ vals,
                                    const float* __restrict__ A,
                                    const int* __restrict__ rows,
                                    const int* __restrict__ cols,
                                    float* __restrict__ out,
                                    int nnz) {
    int t = blockIdx.x * blockDim.x + threadIdx.x;
    int e = t >> 4;
    int q = t & 15;
    if (e >= nnz) return;
    float v = vals[e];
    int   r = rows[e];
    int   c = cols[e];
    const float4 a = *reinterpret_cast<const float4*>(A + (size_t)c * NCOLS + q * 4);
    float* o = out + (size_t)r * NCOLS + q * 4;
    atomicAdd(o + 0, v * a.x);
    atomicAdd(o + 1, v * a.y);
    atomicAdd(o + 2, v * a.z);
    atomicAdd(o + 3, v * a.w);
}

// ---- kernel 1: conv(A->bf16) + block-local counting sort, sequential out ----
__global__ void __launch_bounds__(BT_S)
sort_conv(const float* __restrict__ vals,
          const int* __restrict__ rows,
          const int* __restrict__ cols,
          const float* __restrict__ A,
          uint* __restrict__ Abf,
          int2* __restrict__ pvc,
          int* __restrict__ tab,
          int nnz, int chunk, int NB, int na8, int doconv) {
    __shared__ int2 sorted[CAP_S];        // 64 KB
    __shared__ int  cnt[MAXNB];
    __shared__ int  sc[BT_S];

    int j = blockIdx.x, t = threadIdx.x;

    // phase 0: fold A -> bf16 (RTNE); slice per block
    if (doconv) {
        int e8pb = (na8 + gridDim.x - 1) / gridDim.x;
        int clo = j * e8pb, chi = min(clo + e8pb, na8);
        auto bf = [](uint u) -> uint { return (u + 0x7FFFu + ((u >> 16) & 1u)) >> 16; };
        for (int i = clo + t; i < chi; i += BT_S) {
            int idx = i << 3;
            const uint4 u0 = *reinterpret_cast<const uint4*>(A + idx);
            const uint4 u1 = *reinterpret_cast<const uint4*>(A + idx + 4);
            uint4 o;
            o.x = bf(u0.x) | (bf(u0.y) << 16);
            o.y = bf(u0.z) | (bf(u0.w) << 16);
            o.z = bf(u1.x) | (bf(u1.y) << 16);
            o.w = bf(u1.z) | (bf(u1.w) << 16);
            *reinterpret_cast<uint4*>(Abf + (i << 2)) = o;
        }
    }

    int base = j * chunk;
    int n = nnz - base;
    if (n > chunk) n = chunk;
    if (n < 0) n = 0;
    int nv = n >> 2;

    for (int i = t; i < NB; i += BT_S) cnt[i] = 0;
    __syncthreads();

    // phase 1: histogram (int4 vectorized)
    const int4* r4p = reinterpret_cast<const int4*>(rows + base);
    for (int i = t; i < nv; i += BT_S) {
        int4 r = r4p[i];
        atomicAdd(&cnt[r.x >> RPB_SHIFT], 1);
        atomicAdd(&cnt[r.y >> RPB_SHIFT], 1);
        atomicAdd(&cnt[r.z >> RPB_SHIFT], 1);
        atomicAdd(&cnt[r.w >> RPB_SHIFT], 1);
    }
    for (int i = (nv << 2) + t; i < n; i += BT_S)
        atomicAdd(&cnt[rows[base + i] >> RPB_SHIFT], 1);
    __syncthreads();

    // phase 2: block-wide exclusive scan of cnt[0..NB)
    int spt = (NB + BT_S - 1) / BT_S;
    int lo = t * spt, hi = min(lo + spt, NB);
    int s = 0;
    for (int i = lo; i < hi; ++i) s += cnt[i];
    sc[t] = s;
    __syncthreads();
    for (int off = 1; off < BT_S; off <<= 1) {
        int u = (t >= off) ? sc[t - off] : 0;
        __syncthreads();
        sc[t] += u;
        __syncthreads();
    }
    int run = sc[t] - s;
    for (int i = lo; i < hi; ++i) { int c = cnt[i]; cnt[i] = run; run += c; }
    __syncthreads();

    for (int b = t; b < NB; b += BT_S) tab[(size_t)j * (NB + 1) + b] = base + cnt[b];
    if (t == 0) tab[(size_t)j * (NB + 1) + NB] = base + n;
    __syncthreads();

    // phase 3: scatter into LDS sorted order (vectorized reads)
    const float4* v4p = reinterpret_cast<const float4*>(vals + base);
    const int4*   c4p = reinterpret_cast<const int4*>(cols + base);
    for (int i = t; i < nv; i += BT_S) {
        int4 r = r4p[i]; float4 v = v4p[i]; int4 c = c4p[i];
        int slot;
        slot = atomicAdd(&cnt[r.x >> RPB_SHIFT], 1);
        sorted[slot] = make_int2(__float_as_int(v.x), c.x | ((r.x & (RPB - 1)) << 17));
        slot = atomicAdd(&cnt[r.y >> RPB_SHIFT], 1);
        sorted[slot] = make_int2(__float_as_int(v.y), c.y | ((r.y & (RPB - 1)) << 17));
        slot = atomicAdd(&cnt[r.z >> RPB_SHIFT], 1);
        sorted[slot] = make_int2(__float_as_int(v.z), c.z | ((r.z & (RPB - 1)) << 17));
        slot = atomicAdd(&cnt[r.w >> RPB_SHIFT], 1);
        sorted[slot] = make_int2(__float_as_int(v.w), c.w | ((r.w & (RPB - 1)) << 17));
    }
    for (int i = (nv << 2) + t; i < n; i += BT_S) {
        int e = base + i;
        int r = rows[e];
        int slot = atomicAdd(&cnt[r >> RPB_SHIFT], 1);
        sorted[slot] = make_int2(__float_as_int(vals[e]),
                                 cols[e] | ((r & (RPB - 1)) << 17));
    }
    __syncthreads();

    // phase 4: sequential coalesced writeout
    int4* pvc4 = reinterpret_cast<int4*>(pvc + base);   // base*8 % 16 == 0
    int nh = n >> 1;
    for (int i = t; i < nh; i += BT_S) {
        int2 a = sorted[2 * i], b2 = sorted[2 * i + 1];
        pvc4[i] = make_int4(a.x, a.y, b2.x, b2.y);
    }
    if ((n & 1) && t == 0) pvc[base + n - 1] = sorted[n - 1];
}

// key = (localrow << 3) | shard ; row-major, shard(col)-minor
__device__ __forceinline__ int skey(int y) {
    return (((y >> 17) & (RPB - 1)) << 3) | ((y & 0x1FFFF) >> SH_SHIFT);
}

// ---- kernel 2: per-bucket sort (row-major/shard-minor) + batched reduce ----
// 64 groups x 4 lanes; group owns ONE local row = ONE contiguous run,
// internally column-ascending. Compute loop identical to R14 (4-deep batch).
template<int USEBF>
__global__ void __launch_bounds__(BT)
spmm_reduce_rs(const int2* __restrict__ pvc,
               const int* __restrict__ tab,
               const float* __restrict__ A,
               const uint* __restrict__ Abf,
               float* __restrict__ out,
               int M, int NB) {
    __shared__ int2 sorted[CAP_R];        // 16 KB
    __shared__ int  cnt[NKEY];            // 2 KB
    __shared__ int  off2[NKEY + 1];       // 2 KB
    __shared__ int  sc[BT];               // 1 KB

    int b = blockIdx.x, t = threadIdx.x;
    int sS = tab[(size_t)t * (NB + 1) + b];
    int sE = tab[(size_t)t * (NB + 1) + b + 1];
    int len = sE - sS;

    for (int i = t; i < NKEY; i += BT) cnt[i] = 0;
    __syncthreads();

    // single global pass: register-stage + count (static indices only)
    int2 st[SCAP];
    #pragma unroll
    for (int i = 0; i < SCAP; ++i) {
        if (i < len) {
            st[i] = pvc[sS + i];
            atomicAdd(&cnt[skey(st[i].y)], 1);
        }
    }
    for (int i = SCAP; i < len; ++i)
        atomicAdd(&cnt[skey(pvc[sS + i].y)], 1);
    __syncthreads();

    // block-wide exclusive scan of cnt[0..512): 2 keys per thread
    int k0 = t << 1;
    int c0 = cnt[k0], c1 = cnt[k0 + 1];
    int s = c0 + c1;
    sc[t] = s;
    __syncthreads();
    for (int o = 1; o < BT; o <<= 1) {
        int u = (t >= o) ? sc[t - o] : 0;
        __syncthreads();
        sc[t] += u;
        __syncthreads();
    }
    int run = sc[t] - s;
    off2[k0]     = run;
    off2[k0 + 1] = run + c0;
    cnt[k0]      = run;           // cursor
    cnt[k0 + 1]  = run + c0;
    if (t == BT - 1) off2[NKEY] = sc[t];
    __syncthreads();

    int total = off2[NKEY];
    int row0 = b << RPB_SHIFT;
    int nrow = min(RPB, M - row0);

    if (total > CAP_R) {
        // overflow fallback: correct for any distribution (f32 A path)
        for (int i = t; i < nrow * NCOLS; i += BT) out[(size_t)row0 * NCOLS + i] = 0.f;
        __syncthreads();
        for (int e = sS; e < sE; ++e) {
            int2 vc = pvc[e];
            float v = __int_as_float(vc.x);
            int   c = vc.y & 0x1FFFF;
            int   rl = (vc.y >> 17) & (RPB - 1);
            for (int nn = 0; nn < NCOLS; ++nn)
                atomicAdd(&out[(size_t)(row0 + rl) * NCOLS + nn],
                          v * A[(size_t)c * NCOLS + nn]);
        }
        return;
    }

    // scatter from registers (tail re-reads pvc, L2-hot)
    #pragma unroll
    for (int i = 0; i < SCAP; ++i) {
        if (i < len) {
            int slot = atomicAdd(&cnt[skey(st[i].y)], 1);
            sorted[slot] = st[i];
        }
    }
    for (int i = SCAP; i < len; ++i) {
        int2 vc = pvc[sS + i];
        int slot = atomicAdd(&cnt[skey(vc.y)], 1);
        sorted[slot] = vc;
    }
    __syncthreads();

    // compute: 64 groups x 4 lanes; group grp owns local row grp, one
    // contiguous run (off2[grp*8 .. (grp+1)*8]), column-ascending inside.
    int lane = t & 3;
    int grp  = t >> 2;
    float acc[16];
    #pragma unroll
    for (int i = 0; i < 16; ++i) acc[i] = 0.f;

    int s0 = off2[grp << 3], s1 = off2[(grp + 1) << 3];

    if (USEBF) {
        auto fma16 = [&](uint4 u0, uint4 u1, float v) {
            acc[0]  += v * __uint_as_float(u0.x << 16);
            acc[1]  += v * __uint_as_float(u0.x & 0xFFFF0000u);
            acc[2]  += v * __uint_as_float(u0.y << 16);
            acc[3]  += v * __uint_as_float(u0.y & 0xFFFF0000u);
            acc[4]  += v * __uint_as_float(u0.z << 16);
            acc[5]  += v * __uint_as_float(u0.z & 0xFFFF0000u);
            acc[6]  += v * __uint_as_float(u0.w << 16);
            acc[7]  += v * __uint_as_float(u0.w & 0xFFFF0000u);
            acc[8]  += v * __uint_as_float(u1.x << 16);
            acc[9]  += v * __uint_as_float(u1.x & 0xFFFF0000u);
            acc[10] += v * __uint_as_float(u1.y << 16);
            acc[11] += v * __uint_as_float(u1.y & 0xFFFF0000u);
            acc[12] += v * __uint_as_float(u1.z << 16);
            acc[13] += v * __uint_as_float(u1.z & 0xFFFF0000u);
            acc[14] += v * __uint_as_float(u1.w << 16);
            acc[15] += v * __uint_as_float(u1.w & 0xFFFF0000u);
        };
        int e = s0;
        for (; e + 4 <= s1; e += 4) {
            int2 vc0 = sorted[e], vc1 = sorted[e + 1];
            int2 vc2 = sorted[e + 2], vc3 = sorted[e + 3];
            const uint4* p0 = reinterpret_cast<const uint4*>(
                Abf + ((size_t)(vc0.y & 0x1FFFF) << 5) + (lane << 3));
            const uint4* p1 = reinterpret_cast<const uint4*>(
                Abf + ((size_t)(vc1.y & 0x1FFFF) << 5) + (lane << 3));
            const uint4* p2 = reinterpret_cast<const uint4*>(
                Abf + ((size_t)(vc2.y & 0x1FFFF) << 5) + (lane << 3));
            const uint4* p3 = reinterpret_cast<const uint4*>(
                Abf + ((size_t)(vc3.y & 0x1FFFF) << 5) + (lane << 3));
            uint4 a0 = p0[0], b0 = p0[1];
            uint4 a1 = p1[0], b1 = p1[1];
            uint4 a2 = p2[0], b2 = p2[1];
            uint4 a3 = p3[0], b3 = p3[1];
            fma16(a0, b0, __int_as_float(vc0.x));
            fma16(a1, b1, __int_as_float(vc1.x));
            fma16(a2, b2, __int_as_float(vc2.x));
            fma16(a3, b3, __int_as_float(vc3.x));
        }
        for (; e < s1; ++e) {
            int2 vc = sorted[e];
            const uint4* p = reinterpret_cast<const uint4*>(
                Abf + ((size_t)(vc.y & 0x1FFFF) << 5) + (lane << 3));
            uint4 u0 = p[0], u1 = p[1];
            fma16(u0, u1, __int_as_float(vc.x));
        }
    } else {
        auto fma16f = [&](float4 a0, float4 a1, float4 a2, float4 a3, float v) {
            acc[0]  += v * a0.x; acc[1]  += v * a0.y;
            acc[2]  += v * a0.z; acc[3]  += v * a0.w;
            acc[4]  += v * a1.x; acc[5]  += v * a1.y;
            acc[6]  += v * a1.z; acc[7]  += v * a1.w;
            acc[8]  += v * a2.x; acc[9]  += v * a2.y;
            acc[10] += v * a2.z; acc[11] += v * a2.w;
            acc[12] += v * a3.x; acc[13] += v * a3.y;
            acc[14] += v * a3.z; acc[15] += v * a3.w;
        };
        int e = s0;
        for (; e + 2 <= s1; e += 2) {
            int2 vc0 = sorted[e], vc1 = sorted[e + 1];
            const float4* p0 = reinterpret_cast<const float4*>(
                A + ((size_t)(vc0.y & 0x1FFFF) << 6) + (lane << 4));
            const float4* p1 = reinterpret_cast<const float4*>(
                A + ((size_t)(vc1.y & 0x1FFFF) << 6) + (lane << 4));
            float4 x0 = p0[0], x1 = p0[1], x2 = p0[2], x3 = p0[3];
            float4 y0 = p1[0], y1 = p1[1], y2 = p1[2], y3 = p1[3];
            fma16f(x0, x1, x2, x3, __int_as_float(vc0.x));
            fma16f(y0, y1, y2, y3, __int_as_float(vc1.x));
        }
        for (; e < s1; ++e) {
            int2 vc = sorted[e];
            const float4* p = reinterpret_cast<const float4*>(
                A + ((size_t)(vc.y & 0x1FFFF) << 6) + (lane << 4));
            float4 x0 = p[0], x1 = p[1], x2 = p[2], x3 = p[3];
            fma16f(x0, x1, x2, x3, __int_as_float(vc.x));
        }
    }

    int m = row0 + grp;
    if (m < M) {
        float4* o = reinterpret_cast<float4*>(out + (size_t)m * NCOLS + (lane << 4));
        o[0] = make_float4(acc[0],  acc[1],  acc[2],  acc[3]);
        o[1] = make_float4(acc[4],  acc[5],  acc[6],  acc[7]);
        o[2] = make_float4(acc[8],  acc[9],  acc[10], acc[11]);
        o[3] = make_float4(acc[12], acc[13], acc[14], acc[15]);
    }
}

extern "C" void kernel_launch(void* const* d_in, const int* in_sizes, int n_in,
                              void* d_out, int out_size, void* d_ws, size_t ws_size,
                              hipStream_t stream) {
    const float* vals = (const float*)d_in[0];
    const float* A    = (const float*)d_in[1];
    const int*   rows = (const int*)d_in[2];
    const int*   cols = (const int*)d_in[3];
    float*       out  = (float*)d_out;

    const int nnz = in_sizes[0];
    const int na  = in_sizes[1];           // K * 64
    const int M   = out_size / NCOLS;
    const int K   = na / NCOLS;

    const int NB    = (M + RPB - 1) >> RPB_SHIFT;
    const int chunk = (((nnz + NBLK - 1) / NBLK) + 3) & ~3;   // %4 == 0

    size_t off_tab = 0;
    size_t tab_sz  = (size_t)NBLK * (NB + 1) * 4;
    size_t off_pvc = (off_tab + tab_sz + 15) & ~(size_t)15;
    size_t off_abf = (off_pvc + (size_t)nnz * 8 + 15) & ~(size_t)15;
    size_t need_f32 = off_pvc + (size_t)nnz * 8;
    size_t need_bf  = off_abf + (size_t)na * 2;

    if (need_f32 > ws_size || chunk > CAP_S || NB > MAXNB ||
        K > (1 << 17) || (na & 7) != 0) {
        hipMemsetAsync(d_out, 0, (size_t)out_size * sizeof(float), stream);
        int threads_total = nnz * 16;
        int block = 256;
        int grid = (threads_total + block - 1) / block;
        spmm_scatter_atomic<<<grid, block, 0, stream>>>(vals, A, rows, cols, out, nnz);
        return;
    }

    char* ws = (char*)d_ws;
    int*  tab = (int*)(ws + off_tab);
    int2* pvc = (int2*)(ws + off_pvc);
    uint* abf = (uint*)(ws + off_abf);

    const bool use_bf = (need_bf <= ws_size);
    const int  na8    = na >> 3;

    sort_conv<<<NBLK, BT_S, 0, stream>>>(vals, rows, cols, A, abf, pvc, tab,
                                         nnz, chunk, NB, na8, use_bf ? 1 : 0);
    if (use_bf)
        spmm_reduce_rs<1><<<NB, BT, 0, stream>>>(pvc, tab, A, abf, out, M, NB);
    else
        spmm_reduce_rs<0><<<NB, BT, 0, stream>>>(pvc, tab, A, abf, out, M, NB);
}

// Round 16
// 76.332 us; speedup vs baseline: 1.0236x; 1.0236x over previous
//
#include <hip/hip_runtime.h>
#include <hip/hip_bf16.h>

// out[m, n] = sum_{e : rows[e]==m} vals[e] * A[cols[e], n]
// M = 100000, K = 100000, N = 64, NNZ = 1600000
//
// Round 16 (final): revert to R14 = best measured (76.5us).
//  Pipeline: [sort_conv] conv A->bf16 + block-local counting sort by
//  64-row bucket, amp-1 sequential writeout + tab[block][bucket] index;
//  [spmm_reduce_rs] per-bucket register-staged counting sort + 4-deep
//  batched register reduce (64 groups x 4 lanes), single output write.
//  Reduce is pinned at the random-64B-gather MSHR limit (~2.5-3 TB/s
//  service): 56-60us across 7 structural variants (R9-R15), FETCH
//  119-145 MB with time invariant -> latency-slot bound, not volume.

#define NCOLS      64
#define RPB        64
#define RPB_SHIFT  6
#define NBLK       256         // sort blocks == reduce BT (1 sub-seg per thread)
#define BT         256
#define BT_S       1024        // sort block threads
#define CAP_S      8192        // sort chunk entries (64 KB LDS)
#define CAP_R      2048        // reduce staging entries (16 KB LDS)
#define SCAP       12          // register-staged entries per sub-segment
#define MAXNB      1568

// ---- fallback (round-1 kernel) ----
__global__ void spmm_scatter_atomic(const float* __restrict__ vals,
                                    const float* __restrict__ A,
                                    const int* __restrict__ rows,
                                    const int* __restrict__ cols,
                                    float* __restrict__ out,
                                    int nnz) {
    int t = blockIdx.x * blockDim.x + threadIdx.x;
    int e = t >> 4;
    int q = t & 15;
    if (e >= nnz) return;
    float v = vals[e];
    int   r = rows[e];
    int   c = cols[e];
    const float4 a = *reinterpret_cast<const float4*>(A + (size_t)c * NCOLS + q * 4);
    float* o = out + (size_t)r * NCOLS + q * 4;
    atomicAdd(o + 0, v * a.x);
    atomicAdd(o + 1, v * a.y);
    atomicAdd(o + 2, v * a.z);
    atomicAdd(o + 3, v * a.w);
}

// ---- kernel 1: conv(A->bf16) + block-local counting sort, sequential out ----
__global__ void __launch_bounds__(BT_S)
sort_conv(const float* __restrict__ vals,
          const int* __restrict__ rows,
          const int* __restrict__ cols,
          const float* __restrict__ A,
          uint* __restrict__ Abf,
          int2* __restrict__ pvc,
          int* __restrict__ tab,
          int nnz, int chunk, int NB, int na8, int doconv) {
    __shared__ int2 sorted[CAP_S];        // 64 KB
    __shared__ int  cnt[MAXNB];
    __shared__ int  sc[BT_S];

    int j = blockIdx.x, t = threadIdx.x;

    // phase 0: fold A -> bf16 (RTNE); slice per block
    if (doconv) {
        int e8pb = (na8 + gridDim.x - 1) / gridDim.x;
        int clo = j * e8pb, chi = min(clo + e8pb, na8);
        auto bf = [](uint u) -> uint { return (u + 0x7FFFu + ((u >> 16) & 1u)) >> 16; };
        for (int i = clo + t; i < chi; i += BT_S) {
            int idx = i << 3;
            const uint4 u0 = *reinterpret_cast<const uint4*>(A + idx);
            const uint4 u1 = *reinterpret_cast<const uint4*>(A + idx + 4);
            uint4 o;
            o.x = bf(u0.x) | (bf(u0.y) << 16);
            o.y = bf(u0.z) | (bf(u0.w) << 16);
            o.z = bf(u1.x) | (bf(u1.y) << 16);
            o.w = bf(u1.z) | (bf(u1.w) << 16);
            *reinterpret_cast<uint4*>(Abf + (i << 2)) = o;
        }
    }

    int base = j * chunk;
    int n = nnz - base;
    if (n > chunk) n = chunk;
    if (n < 0) n = 0;
    int nv = n >> 2;

    for (int i = t; i < NB; i += BT_S) cnt[i] = 0;
    __syncthreads();

    // phase 1: histogram (int4 vectorized)
    const int4* r4p = reinterpret_cast<const int4*>(rows + base);
    for (int i = t; i < nv; i += BT_S) {
        int4 r = r4p[i];
        atomicAdd(&cnt[r.x >> RPB_SHIFT], 1);
        atomicAdd(&cnt[r.y >> RPB_SHIFT], 1);
        atomicAdd(&cnt[r.z >> RPB_SHIFT], 1);
        atomicAdd(&cnt[r.w >> RPB_SHIFT], 1);
    }
    for (int i = (nv << 2) + t; i < n; i += BT_S)
        atomicAdd(&cnt[rows[base + i] >> RPB_SHIFT], 1);
    __syncthreads();

    // phase 2: block-wide exclusive scan of cnt[0..NB)
    int spt = (NB + BT_S - 1) / BT_S;
    int lo = t * spt, hi = min(lo + spt, NB);
    int s = 0;
    for (int i = lo; i < hi; ++i) s += cnt[i];
    sc[t] = s;
    __syncthreads();
    for (int off = 1; off < BT_S; off <<= 1) {
        int u = (t >= off) ? sc[t - off] : 0;
        __syncthreads();
        sc[t] += u;
        __syncthreads();
    }
    int run = sc[t] - s;
    for (int i = lo; i < hi; ++i) { int c = cnt[i]; cnt[i] = run; run += c; }
    __syncthreads();

    for (int b = t; b < NB; b += BT_S) tab[(size_t)j * (NB + 1) + b] = base + cnt[b];
    if (t == 0) tab[(size_t)j * (NB + 1) + NB] = base + n;
    __syncthreads();

    // phase 3: scatter into LDS sorted order (vectorized reads)
    const float4* v4p = reinterpret_cast<const float4*>(vals + base);
    const int4*   c4p = reinterpret_cast<const int4*>(cols + base);
    for (int i = t; i < nv; i += BT_S) {
        int4 r = r4p[i]; float4 v = v4p[i]; int4 c = c4p[i];
        int slot;
        slot = atomicAdd(&cnt[r.x >> RPB_SHIFT], 1);
        sorted[slot] = make_int2(__float_as_int(v.x), c.x | ((r.x & (RPB - 1)) << 17));
        slot = atomicAdd(&cnt[r.y >> RPB_SHIFT], 1);
        sorted[slot] = make_int2(__float_as_int(v.y), c.y | ((r.y & (RPB - 1)) << 17));
        slot = atomicAdd(&cnt[r.z >> RPB_SHIFT], 1);
        sorted[slot] = make_int2(__float_as_int(v.z), c.z | ((r.z & (RPB - 1)) << 17));
        slot = atomicAdd(&cnt[r.w >> RPB_SHIFT], 1);
        sorted[slot] = make_int2(__float_as_int(v.w), c.w | ((r.w & (RPB - 1)) << 17));
    }
    for (int i = (nv << 2) + t; i < n; i += BT_S) {
        int e = base + i;
        int r = rows[e];
        int slot = atomicAdd(&cnt[r >> RPB_SHIFT], 1);
        sorted[slot] = make_int2(__float_as_int(vals[e]),
                                 cols[e] | ((r & (RPB - 1)) << 17));
    }
    __syncthreads();

    // phase 4: sequential coalesced writeout
    int4* pvc4 = reinterpret_cast<int4*>(pvc + base);   // base*8 % 16 == 0
    int nh = n >> 1;
    for (int i = t; i < nh; i += BT_S) {
        int2 a = sorted[2 * i], b2 = sorted[2 * i + 1];
        pvc4[i] = make_int4(a.x, a.y, b2.x, b2.y);
    }
    if ((n & 1) && t == 0) pvc[base + n - 1] = sorted[n - 1];
}

// ---- kernel 2: per-bucket register-staged sort + pipelined reduce ----
// 64 groups x 4 lanes; group owns ONE local row; 4-entry batched gather.
template<int USEBF>
__global__ void __launch_bounds__(BT)
spmm_reduce_rs(const int2* __restrict__ pvc,
               const int* __restrict__ tab,
               const float* __restrict__ A,
               const uint* __restrict__ Abf,
               float* __restrict__ out,
               int M, int NB) {
    __shared__ int2 sorted[CAP_R];        // 16 KB
    __shared__ int  cnt[RPB];
    __shared__ int  off[RPB + 1];

    int b = blockIdx.x, t = threadIdx.x;
    int sS = tab[(size_t)t * (NB + 1) + b];
    int sE = tab[(size_t)t * (NB + 1) + b + 1];
    int len = sE - sS;

    if (t < RPB) cnt[t] = 0;
    __syncthreads();

    // single global pass: register-stage + count (static indices only)
    int2 st[SCAP];
    #pragma unroll
    for (int i = 0; i < SCAP; ++i) {
        if (i < len) {
            st[i] = pvc[sS + i];
            atomicAdd(&cnt[(st[i].y >> 17) & (RPB - 1)], 1);
        }
    }
    for (int i = SCAP; i < len; ++i)
        atomicAdd(&cnt[(pvc[sS + i].y >> 17) & (RPB - 1)], 1);
    __syncthreads();

    // exclusive scan of 64 counters (wave 0)
    if (t < RPB) {
        int v = cnt[t];
        int s = v;
        #pragma unroll
        for (int d = 1; d < RPB; d <<= 1) {
            int u = __shfl_up(s, d, 64);
            if (t >= d) s += u;
        }
        off[t + 1] = s;
        if (t == 0) off[0] = 0;
        cnt[t] = s - v;               // cursor
    }
    __syncthreads();

    int total = off[RPB];
    int row0 = b << RPB_SHIFT;
    int nrow = min(RPB, M - row0);

    if (total > CAP_R) {
        // overflow fallback: correct for any distribution (f32 A path)
        for (int i = t; i < nrow * NCOLS; i += BT) out[(size_t)row0 * NCOLS + i] = 0.f;
        __syncthreads();
        for (int e = sS; e < sE; ++e) {
            int2 vc = pvc[e];
            float v = __int_as_float(vc.x);
            int   c = vc.y & 0x1FFFF;
            int   rl = (vc.y >> 17) & (RPB - 1);
            for (int nn = 0; nn < NCOLS; ++nn)
                atomicAdd(&out[(size_t)(row0 + rl) * NCOLS + nn],
                          v * A[(size_t)c * NCOLS + nn]);
        }
        return;
    }

    // scatter from registers (tail re-reads pvc, L2-hot)
    #pragma unroll
    for (int i = 0; i < SCAP; ++i) {
        if (i < len) {
            int slot = atomicAdd(&cnt[(st[i].y >> 17) & (RPB - 1)], 1);
            sorted[slot] = st[i];
        }
    }
    for (int i = SCAP; i < len; ++i) {
        int2 vc = pvc[sS + i];
        int slot = atomicAdd(&cnt[(vc.y >> 17) & (RPB - 1)], 1);
        sorted[slot] = vc;
    }
    __syncthreads();

    // compute: 64 groups x 4 lanes; group grp owns local row grp.
    // 4-entry batched pipeline: issue all 8 uint4 loads, then FMA.
    int lane = t & 3;
    int grp  = t >> 2;
    float acc[16];
    #pragma unroll
    for (int i = 0; i < 16; ++i) acc[i] = 0.f;

    int s0 = off[grp], s1 = off[grp + 1];

    if (USEBF) {
        auto fma16 = [&](uint4 u0, uint4 u1, float v) {
            acc[0]  += v * __uint_as_float(u0.x << 16);
            acc[1]  += v * __uint_as_float(u0.x & 0xFFFF0000u);
            acc[2]  += v * __uint_as_float(u0.y << 16);
            acc[3]  += v * __uint_as_float(u0.y & 0xFFFF0000u);
            acc[4]  += v * __uint_as_float(u0.z << 16);
            acc[5]  += v * __uint_as_float(u0.z & 0xFFFF0000u);
            acc[6]  += v * __uint_as_float(u0.w << 16);
            acc[7]  += v * __uint_as_float(u0.w & 0xFFFF0000u);
            acc[8]  += v * __uint_as_float(u1.x << 16);
            acc[9]  += v * __uint_as_float(u1.x & 0xFFFF0000u);
            acc[10] += v * __uint_as_float(u1.y << 16);
            acc[11] += v * __uint_as_float(u1.y & 0xFFFF0000u);
            acc[12] += v * __uint_as_float(u1.z << 16);
            acc[13] += v * __uint_as_float(u1.z & 0xFFFF0000u);
            acc[14] += v * __uint_as_float(u1.w << 16);
            acc[15] += v * __uint_as_float(u1.w & 0xFFFF0000u);
        };
        int e = s0;
        for (; e + 4 <= s1; e += 4) {
            int2 vc0 = sorted[e], vc1 = sorted[e + 1];
            int2 vc2 = sorted[e + 2], vc3 = sorted[e + 3];
            const uint4* p0 = reinterpret_cast<const uint4*>(
                Abf + ((size_t)(vc0.y & 0x1FFFF) << 5) + (lane << 3));
            const uint4* p1 = reinterpret_cast<const uint4*>(
                Abf + ((size_t)(vc1.y & 0x1FFFF) << 5) + (lane << 3));
            const uint4* p2 = reinterpret_cast<const uint4*>(
                Abf + ((size_t)(vc2.y & 0x1FFFF) << 5) + (lane << 3));
            const uint4* p3 = reinterpret_cast<const uint4*>(
                Abf + ((size_t)(vc3.y & 0x1FFFF) << 5) + (lane << 3));
            uint4 a0 = p0[0], b0 = p0[1];
            uint4 a1 = p1[0], b1 = p1[1];
            uint4 a2 = p2[0], b2 = p2[1];
            uint4 a3 = p3[0], b3 = p3[1];
            fma16(a0, b0, __int_as_float(vc0.x));
            fma16(a1, b1, __int_as_float(vc1.x));
            fma16(a2, b2, __int_as_float(vc2.x));
            fma16(a3, b3, __int_as_float(vc3.x));
        }
        for (; e < s1; ++e) {
            int2 vc = sorted[e];
            const uint4* p = reinterpret_cast<const uint4*>(
                Abf + ((size_t)(vc.y & 0x1FFFF) << 5) + (lane << 3));
            uint4 u0 = p[0], u1 = p[1];
            fma16(u0, u1, __int_as_float(vc.x));
        }
    } else {
        auto fma16f = [&](float4 a0, float4 a1, float4 a2, float4 a3, float v) {
            acc[0]  += v * a0.x; acc[1]  += v * a0.y;
            acc[2]  += v * a0.z; acc[3]  += v * a0.w;
            acc[4]  += v * a1.x; acc[5]  += v * a1.y;
            acc[6]  += v * a1.z; acc[7]  += v * a1.w;
            acc[8]  += v * a2.x; acc[9]  += v * a2.y;
            acc[10] += v * a2.z; acc[11] += v * a2.w;
            acc[12] += v * a3.x; acc[13] += v * a3.y;
            acc[14] += v * a3.z; acc[15] += v * a3.w;
        };
        int e = s0;
        for (; e + 2 <= s1; e += 2) {
            int2 vc0 = sorted[e], vc1 = sorted[e + 1];
            const float4* p0 = reinterpret_cast<const float4*>(
                A + ((size_t)(vc0.y & 0x1FFFF) << 6) + (lane << 4));
            const float4* p1 = reinterpret_cast<const float4*>(
                A + ((size_t)(vc1.y & 0x1FFFF) << 6) + (lane << 4));
            float4 x0 = p0[0], x1 = p0[1], x2 = p0[2], x3 = p0[3];
            float4 y0 = p1[0], y1 = p1[1], y2 = p1[2], y3 = p1[3];
            fma16f(x0, x1, x2, x3, __int_as_float(vc0.x));
            fma16f(y0, y1, y2, y3, __int_as_float(vc1.x));
        }
        for (; e < s1; ++e) {
            int2 vc = sorted[e];
            const float4* p = reinterpret_cast<const float4*>(
                A + ((size_t)(vc.y & 0x1FFFF) << 6) + (lane << 4));
            float4 x0 = p[0], x1 = p[1], x2 = p[2], x3 = p[3];
            fma16f(x0, x1, x2, x3, __int_as_float(vc.x));
        }
    }

    int m = row0 + grp;
    if (m < M) {
        float4* o = reinterpret_cast<float4*>(out + (size_t)m * NCOLS + (lane << 4));
        o[0] = make_float4(acc[0],  acc[1],  acc[2],  acc[3]);
        o[1] = make_float4(acc[4],  acc[5],  acc[6],  acc[7]);
        o[2] = make_float4(acc[8],  acc[9],  acc[10], acc[11]);
        o[3] = make_float4(acc[12], acc[13], acc[14], acc[15]);
    }
}

extern "C" void kernel_launch(void* const* d_in, const int* in_sizes, int n_in,
                              void* d_out, int out_size, void* d_ws, size_t ws_size,
                              hipStream_t stream) {
    const float* vals = (const float*)d_in[0];
    const float* A    = (const float*)d_in[1];
    const int*   rows = (const int*)d_in[2];
    const int*   cols = (const int*)d_in[3];
    float*       out  = (float*)d_out;

    const int nnz = in_sizes[0];
    const int na  = in_sizes[1];           // K * 64
    const int M   = out_size / NCOLS;
    const int K   = na / NCOLS;

    const int NB    = (M + RPB - 1) >> RPB_SHIFT;
    const int chunk = (((nnz + NBLK - 1) / NBLK) + 3) & ~3;   // %4 == 0

    size_t off_tab = 0;
    size_t tab_sz  = (size_t)NBLK * (NB + 1) * 4;
    size_t off_pvc = (off_tab + tab_sz + 15) & ~(size_t)15;
    size_t off_abf = (off_pvc + (size_t)nnz * 8 + 15) & ~(size_t)15;
    size_t need_f32 = off_pvc + (size_t)nnz * 8;
    size_t need_bf  = off_abf + (size_t)na * 2;

    if (need_f32 > ws_size || chunk > CAP_S || NB > MAXNB ||
        K > (1 << 17) || (na & 7) != 0) {
        hipMemsetAsync(d_out, 0, (size_t)out_size * sizeof(float), stream);
        int threads_total = nnz * 16;
        int block = 256;
        int grid = (threads_total + block - 1) / block;
        spmm_scatter_atomic<<<grid, block, 0, stream>>>(vals, A, rows, cols, out, nnz);
        return;
    }

    char* ws = (char*)d_ws;
    int*  tab = (int*)(ws + off_tab);
    int2* pvc = (int2*)(ws + off_pvc);
    uint* abf = (uint*)(ws + off_abf);

    const bool use_bf = (need_bf <= ws_size);
    const int  na8    = na >> 3;

    sort_conv<<<NBLK, BT_S, 0, stream>>>(vals, rows, cols, A, abf, pvc, tab,
                                         nnz, chunk, NB, na8, use_bf ? 1 : 0);
    if (use_bf)
        spmm_reduce_rs<1><<<NB, BT, 0, stream>>>(pvc, tab, A, abf, out, M, NB);
    else
        spmm_reduce_rs<0><<<NB, BT, 0, stream>>>(pvc, tab, A, abf, out, M, NB);
}